// Round 8
// baseline (71.789 us; speedup 1.0000x reference)
//
#include <hip/hip_runtime.h>
#include <hip/hip_bf16.h>

#define NELEM 16384
#define DIN 768
#define DMID 128
#define DOUT 4

typedef __attribute__((ext_vector_type(8))) short short8;
typedef __attribute__((ext_vector_type(4))) float f32x4;

__device__ __forceinline__ unsigned f2bf(float f) {
    unsigned u = __float_as_uint(f);
    return (u + 0x7FFFu + ((u >> 16) & 1u)) >> 16;   // RNE bf16
}

// word = vocab<<14 | e (e = b*512+s); key = word>>9; idx = word&16383;
// vocab = word>>14; batch = (word>>9)&31.

// ===========================================================================
// FAST PATH ws layout:
//   P0@0(64K) P1@65536(64K) hist0@131072(64K) hist1@196608(64K) hist2@262144(64K)
//   RS@327680(32772B) WtG@360512(192K) bar@557120(264B: counter,gen,gsum[64])
// hist layout: hist[d*64 + block].
// ===========================================================================
#define FAST_WS 557384
#define SORT_BLOCKS 64

__device__ __forceinline__ void gsync(unsigned* bar) {
    __syncthreads();
    if (threadIdx.x == 0) {
        unsigned g = __hip_atomic_load(&bar[1], __ATOMIC_ACQUIRE, __HIP_MEMORY_SCOPE_AGENT);
        unsigned a = __hip_atomic_fetch_add(&bar[0], 1u, __ATOMIC_ACQ_REL, __HIP_MEMORY_SCOPE_AGENT);
        if (a + 1u == (unsigned)SORT_BLOCKS) {
            __hip_atomic_store(&bar[0], 0u, __ATOMIC_RELAXED, __HIP_MEMORY_SCOPE_AGENT);
            __hip_atomic_store(&bar[1], g + 1u, __ATOMIC_RELEASE, __HIP_MEMORY_SCOPE_AGENT);
        } else {
            while (__hip_atomic_load(&bar[1], __ATOMIC_ACQUIRE, __HIP_MEMORY_SCOPE_AGENT) == g) {
                __builtin_amdgcn_s_sleep(2);
            }
        }
    }
    __syncthreads();
}

// K1: blocks 0..63: build words + pass-0 hist + zero hist1/2 + zero bar counter.
//     blocks 64..447: W1^T -> bf16.
__global__ __launch_bounds__(256) void prep_kernel(
    const int* __restrict__ vocab_ids, const float* __restrict__ W1,
    unsigned* __restrict__ P0, unsigned* __restrict__ hist0,
    unsigned* __restrict__ histZ, unsigned short* __restrict__ WtG,
    unsigned* __restrict__ bar) {
    const int t = threadIdx.x;
    const int bx = blockIdx.x;
    if (bx < 64) {
        __shared__ unsigned h[256];
        h[t] = 0;
        int e = bx * 256 + t;
        unsigned word = ((unsigned)vocab_ids[e] << 14) | (unsigned)e;
        P0[e] = word;
        __syncthreads();
        atomicAdd(&h[(word >> 9) & 255u], 1u);
        __syncthreads();
        hist0[t * 64 + bx] = h[t];
        histZ[bx * 512 + t] = 0;                 // zero hist1+hist2 (contiguous 128KB)
        histZ[bx * 512 + 256 + t] = 0;
        if (bx == 0 && t == 0) bar[0] = 0;       // barrier counter (gen left as-is)
    } else {
        int idx = (bx - 64) * 256 + t;           // 0..98303
        int c = idx / DIN;
        int k = idx - c * DIN;
        WtG[idx] = (unsigned short)f2bf(W1[k * DMID + c]);
    }
}

// one stable scatter pass (256 elems per block, 64 blocks)
template <bool HASNEXT>
__device__ __forceinline__ void scatter_pass(
    const unsigned* __restrict__ src, unsigned* __restrict__ dst,
    const unsigned* __restrict__ histCur, unsigned* __restrict__ histNext,
    int shift, int nshift, int blk, int t,
    unsigned* base_lds, unsigned* whist, unsigned* wsum) {
    const int lane = t & 63;
    const int w = t >> 6;

    unsigned x = src[blk * 256 + t];
    unsigned d = (x >> shift) & 255u;

    whist[t] = 0; whist[256 + t] = 0; whist[512 + t] = 0; whist[768 + t] = 0;

    // digit-row scan: rowsum over all 64 blocks + prefix over blocks < blk
    unsigned rowsum = 0, myprefix = 0;
    const uint4* row = (const uint4*)(histCur + t * 64);
#pragma unroll
    for (int q = 0; q < 16; ++q) {
        uint4 h4 = row[q];
        int b = q * 4;
        rowsum += h4.x + h4.y + h4.z + h4.w;
        if (b + 0 < blk) myprefix += h4.x;
        if (b + 1 < blk) myprefix += h4.y;
        if (b + 2 < blk) myprefix += h4.z;
        if (b + 3 < blk) myprefix += h4.w;
    }
    // block-exclusive scan of 256 digit rowsums
    unsigned inc = rowsum;
#pragma unroll
    for (int off = 1; off < 64; off <<= 1) {
        unsigned y = __shfl_up(inc, off);
        if (lane >= off) inc += y;
    }
    if (lane == 63) wsum[w] = inc;
    __syncthreads();
    unsigned wo = 0;
    for (int w2 = 0; w2 < w; ++w2) wo += wsum[w2];
    base_lds[t] = wo + (inc - rowsum) + myprefix;

    // stable in-wave rank via 8-ballot match-any
    unsigned long long m = ~0ull;
#pragma unroll
    for (int bit = 0; bit < 8; ++bit) {
        unsigned long long bb = __ballot((d >> bit) & 1u);
        m &= ((d >> bit) & 1u) ? bb : ~bb;
    }
    int inrank = __popcll(m & ((1ull << lane) - 1ull));
    if (inrank == 0) whist[w * 256 + d] = (unsigned)__popcll(m);
    __syncthreads();
    unsigned cross = 0;
    for (int w2 = 0; w2 < w; ++w2) cross += whist[w2 * 256 + d];
    unsigned dstpos = base_lds[d] + cross + (unsigned)inrank;
    dst[dstpos] = x;
    if (HASNEXT) {
        unsigned dn = (x >> nshift) & 255u;
        atomicAdd(&histNext[dn * 64 + (dstpos >> 8)], 1u);   // order-independent
    }
}

// K2: 64-block cooperative sort (3 passes) + unique + RS + ids.
__global__ __launch_bounds__(256) void coop_sort_kernel(
    unsigned* __restrict__ P0, unsigned* __restrict__ P1,
    const unsigned* __restrict__ hist0, unsigned* __restrict__ hist1,
    unsigned* __restrict__ hist2,
    unsigned short* __restrict__ RS, float* __restrict__ out_ids,
    unsigned* __restrict__ bar) {
    __shared__ unsigned base_lds[256];
    __shared__ unsigned whist[4 * 256];
    __shared__ unsigned wsum[4];
    const int t = threadIdx.x;
    const int blk = blockIdx.x;
    unsigned* gsum = bar + 2;

    scatter_pass<true >(P0, P1, hist0, hist1, 9, 17, blk, t, base_lds, whist, wsum);
    gsync(bar);
    scatter_pass<true >(P1, P0, hist1, hist2, 17, 25, blk, t, base_lds, whist, wsum);
    gsync(bar);
    scatter_pass<false>(P0, P1, hist2, nullptr, 25, 0, blk, t, base_lds, whist, wsum);
    gsync(bar);

    // ---- unique phase A: per-block flag count ----
    const int e = blk * 256 + t;
    const int lane = t & 63;
    const int w = t >> 6;
    unsigned word = P1[e];
    unsigned key = word >> 9;
    bool f = (e == 0) || ((P1[e - 1] >> 9) != key);
    unsigned long long bb = __ballot(f ? 1 : 0);
    unsigned lrank = (unsigned)__popcll(bb & ((1ull << lane) - 1ull));
    if (lane == 0) wsum[w] = (unsigned)__popcll(bb);
    __syncthreads();
    unsigned woff = 0, btot = 0;
#pragma unroll
    for (int w2 = 0; w2 < 4; ++w2) {
        if (w2 < w) woff += wsum[w2];
        btot += wsum[w2];
    }
    if (t == 0) gsum[blk] = btot;
    gsync(bar);
    // ---- unique phase B: cross-block prefix + writes ----
    unsigned prefix = 0, U = 0;
#pragma unroll
    for (int b = 0; b < 64; ++b) {
        unsigned g = gsum[b];
        if (b < blk) prefix += g;
        U += g;
    }
    if (f) {
        unsigned r = prefix + woff + lrank;
        RS[r] = (unsigned short)e;
        out_ids[2 * r + 0] = (float)(word >> 14);
        out_ids[2 * r + 1] = (float)(key & 31u);
    }
    if ((unsigned)e >= U) {
        RS[e] = (unsigned short)NELEM;
        out_ids[2 * e + 0] = 0.0f;
        out_ids[2 * e + 1] = 0.0f;
    }
    if (e == 0) RS[NELEM] = (unsigned short)NELEM;
}

// ===========================================================================
// FALLBACK (proven R6 path) if ws is too small.
// ===========================================================================
#define SORT_SMEM (65536 + 65536 + 4096 + 64)

__global__ __launch_bounds__(1024) void sort_transpose_kernel(
    const int* __restrict__ vocab_ids,
    const float* __restrict__ W1,
    unsigned int* __restrict__ G,
    unsigned short* __restrict__ RS,
    unsigned short* __restrict__ WtG,
    float* __restrict__ out_ids) {
    const int t = threadIdx.x;
    if (blockIdx.x != 0) {
        int idx = (blockIdx.x - 1) * 1024 + t;
        if (idx < DMID * DIN) {
            int c = idx / DIN;
            int k = idx - c * DIN;
            WtG[idx] = (unsigned short)f2bf(W1[k * DMID + c]);
        }
        return;
    }
    extern __shared__ char smem[];
    unsigned* Gs     = (unsigned*)smem;
    unsigned* histDM = (unsigned*)(smem + 65536);
    unsigned* sums   = (unsigned*)(smem + 131072);
    unsigned* totalU = (unsigned*)(smem + 135168);

    for (int e = t; e < NELEM; e += 1024)
        Gs[e] = ((unsigned)vocab_ids[e] << 14) | (unsigned)e;
    __syncthreads();

    for (int pass = 0; pass < 6; ++pass) {
        const int shift = 9 + pass * 4;
        unsigned v[16];
#pragma unroll
        for (int i = 0; i < 16; ++i) v[i] = Gs[t * 16 + i];
#pragma unroll
        for (int d = 0; d < 16; ++d) histDM[d * 1024 + t] = 0;
#pragma unroll
        for (int i = 0; i < 16; ++i) histDM[((v[i] >> shift) & 15u) * 1024 + t] += 1;
        __syncthreads();
        unsigned lex[16]; unsigned run = 0;
#pragma unroll
        for (int i = 0; i < 16; ++i) { unsigned x = histDM[t * 16 + i]; lex[i] = run; run += x; }
        sums[t] = run;
        __syncthreads();
        if (t < 64) {
            unsigned s[16]; unsigned tot = 0;
#pragma unroll
            for (int i = 0; i < 16; ++i) { unsigned x = sums[t * 16 + i]; s[i] = tot; tot += x; }
            unsigned incv = tot;
#pragma unroll
            for (int off = 1; off < 64; off <<= 1) {
                unsigned y = __shfl_up(incv, off);
                if (t >= off) incv += y;
            }
            unsigned excl = incv - tot;
#pragma unroll
            for (int i = 0; i < 16; ++i) sums[t * 16 + i] = excl + s[i];
        }
        __syncthreads();
#pragma unroll
        for (int i = 0; i < 16; ++i) histDM[t * 16 + i] = sums[t] + lex[i];
        __syncthreads();
        unsigned mycnt[16];
#pragma unroll
        for (int d = 0; d < 16; ++d) mycnt[d] = histDM[d * 1024 + t];
#pragma unroll
        for (int i = 0; i < 16; ++i) {
            unsigned d = (v[i] >> shift) & 15u;
            Gs[mycnt[d]++] = v[i];
        }
        __syncthreads();
    }

    unsigned v[16];
#pragma unroll
    for (int i = 0; i < 16; ++i) v[i] = Gs[t * 16 + i];
    unsigned pk = (t == 0) ? 0xFFFFFFFFu : (Gs[t * 16 - 1] >> 9);
    unsigned fm = 0;
#pragma unroll
    for (int i = 0; i < 16; ++i) {
        unsigned key = v[i] >> 9;
        if (key != pk) fm |= (1u << i);
        pk = key;
    }
    sums[t] = (unsigned)__popc(fm);
    __syncthreads();
    if (t < 64) {
        unsigned s[16]; unsigned tot = 0;
#pragma unroll
        for (int i = 0; i < 16; ++i) { unsigned x = sums[t * 16 + i]; s[i] = tot; tot += x; }
        unsigned incv = tot;
#pragma unroll
        for (int off = 1; off < 64; off <<= 1) {
            unsigned y = __shfl_up(incv, off);
            if (t >= off) incv += y;
        }
        unsigned excl = incv - tot;
#pragma unroll
        for (int i = 0; i < 16; ++i) sums[t * 16 + i] = excl + s[i];
        if (t == 63) *totalU = incv;
    }
    __syncthreads();
    unsigned r = sums[t];
#pragma unroll
    for (int i = 0; i < 16; ++i) {
        if (fm & (1u << i)) {
            RS[r] = (unsigned short)(t * 16 + i);
            out_ids[2 * r + 0] = (float)(v[i] >> 14);
            out_ids[2 * r + 1] = (float)((v[i] >> 9) & 31u);
            ++r;
        }
    }
    const unsigned U = *totalU;
    for (int u = t; u < NELEM; u += 1024) {
        if ((unsigned)u >= U) {
            RS[u] = (unsigned short)NELEM;
            out_ids[2 * u + 0] = 0.0f;
            out_ids[2 * u + 1] = 0.0f;
        }
        G[u] = Gs[u];
    }
    if (t == 0) RS[NELEM] = (unsigned short)NELEM;
}

// ===========================================================================
// K3: MFMA fused kernel (proven). 1024 blocks x 256 thr, 16 rows/block.
// ===========================================================================
#define FBM 16
__global__ __launch_bounds__(256) void fused_kernel(
    const unsigned* __restrict__ G,
    const unsigned short* __restrict__ RS,
    const unsigned short* __restrict__ WtG,
    const float* __restrict__ emb,
    const float* __restrict__ b1,
    const float* __restrict__ enc,
    float* __restrict__ out_enc) {
    __shared__ char smem[20736];

    const int t = threadIdx.x;
    const int u0 = blockIdx.x * FBM;
    const int l = t & 63;
    const int w = t >> 6;

    const int ar = t >> 4;
    const int ak4 = t & 15;
    const int rs_a = (int)RS[u0 + ar];
    const int re_a = (int)RS[u0 + ar + 1];

    f32x4 acc0 = {0.f, 0.f, 0.f, 0.f};
    f32x4 acc1 = {0.f, 0.f, 0.f, 0.f};

    for (int kk = 0; kk < DIN; kk += 64) {
        __syncthreads();
        {
            float s0 = 0.f, s1 = 0.f, s2 = 0.f, s3 = 0.f;
            const float* base = emb + (size_t)(kk + ak4 * 4);
            for (int p = rs_a; p < re_a; ++p) {
                unsigned idx = G[p] & 16383u;
                const float4 e4 = *(const float4*)(base + (size_t)idx * DIN);
                s0 += e4.x; s1 += e4.y; s2 += e4.z; s3 += e4.w;
            }
            uint2 packed;
            packed.x = f2bf(s0) | (f2bf(s1) << 16);
            packed.y = f2bf(s2) | (f2bf(s3) << 16);
            *(uint2*)(smem + ar * 144 + ak4 * 8) = packed;
        }
        {
#pragma unroll
            for (int i = 0; i < 4; ++i) {
                int q = t + i * 256;
                int c = q >> 3;
                int uo = q & 7;
                uint4 dv = *(const uint4*)(WtG + (size_t)c * DIN + kk + uo * 8);
                *(uint4*)(smem + 2304 + c * 144 + uo * 16) = dv;
            }
        }
        __syncthreads();
        {
            const int arow = l & 15;
            const int ull = l >> 4;
#pragma unroll
            for (int kf = 0; kf < 2; ++kf) {
                short8 aF = *(const short8*)(smem + arow * 144 + kf * 64 + ull * 16);
                short8 bF0 = *(const short8*)(smem + 2304 + (w * 32 + arow) * 144 + kf * 64 + ull * 16);
                short8 bF1 = *(const short8*)(smem + 2304 + (w * 32 + 16 + arow) * 144 + kf * 64 + ull * 16);
                acc0 = __builtin_amdgcn_mfma_f32_16x16x32_bf16(aF, bF0, acc0, 0, 0, 0);
                acc1 = __builtin_amdgcn_mfma_f32_16x16x32_bf16(aF, bF1, acc1, 0, 0, 0);
            }
        }
    }
    __syncthreads();
    {
        float* Hs = (float*)smem;
        const int col0 = w * 32 + (l & 15);
        const int rbase = (l >> 4) * 4;
#pragma unroll
        for (int reg = 0; reg < 4; ++reg) {
            Hs[(rbase + reg) * 132 + col0] = tanhf(acc0[reg] + b1[col0]);
            Hs[(rbase + reg) * 132 + col0 + 16] = tanhf(acc1[reg] + b1[col0 + 16]);
        }
    }
    __syncthreads();
    {
        const float* Hs = (const float*)smem;
        const int r = t >> 4;
        const int g = t & 15;
        const int u = u0 + r;
        const int rs = (int)RS[u];
        const int re = (int)RS[u + 1];
        unsigned vocab = (rs < re) ? (G[rs] >> 14) : 0u;
        const float4* wrow = (const float4*)(enc + (size_t)vocab * (DMID * DOUT));
        float ax = 0.f, ay = 0.f, az = 0.f, aw = 0.f;
#pragma unroll
        for (int jj = 0; jj < 8; ++jj) {
            int j = jj * 16 + g;
            float4 w4 = wrow[j];
            float hv = Hs[r * 132 + j];
            ax += hv * w4.x; ay += hv * w4.y; az += hv * w4.z; aw += hv * w4.w;
        }
#pragma unroll
        for (int off = 1; off < 16; off <<= 1) {
            ax += __shfl_xor(ax, off);
            ay += __shfl_xor(ay, off);
            az += __shfl_xor(az, off);
            aw += __shfl_xor(aw, off);
        }
        if (g == 0) {
            float4 o;
            o.x = 1.f / (1.f + expf(-ax));
            o.y = 1.f / (1.f + expf(-ay));
            o.z = 1.f / (1.f + expf(-az));
            o.w = 1.f / (1.f + expf(-aw));
            *(float4*)(out_enc + (size_t)u * 4) = o;
        }
    }
}

// ---------------------------------------------------------------------------
extern "C" void kernel_launch(void* const* d_in, const int* in_sizes, int n_in,
                              void* d_out, int out_size, void* d_ws, size_t ws_size,
                              hipStream_t stream) {
    const int*   vocab_ids = (const int*)d_in[0];
    const float* emb       = (const float*)d_in[1];
    const float* W1        = (const float*)d_in[2];
    const float* b1        = (const float*)d_in[3];
    const float* enc       = (const float*)d_in[4];
    float* out = (float*)d_out;

    float* out_ids = out;               // 32768 f32
    float* out_enc = out + NELEM * 2;   // 65536 f32

    char* ws = (char*)d_ws;

    if (ws_size >= FAST_WS) {
        unsigned*       P0    = (unsigned*)(ws + 0);
        unsigned*       P1    = (unsigned*)(ws + 65536);
        unsigned*       hist0 = (unsigned*)(ws + 131072);
        unsigned*       hist1 = (unsigned*)(ws + 196608);
        unsigned*       hist2 = (unsigned*)(ws + 262144);
        unsigned short* RS    = (unsigned short*)(ws + 327680);
        unsigned short* WtG   = (unsigned short*)(ws + 360512);
        unsigned*       bar   = (unsigned*)(ws + 557120);

        prep_kernel<<<448, 256, 0, stream>>>(vocab_ids, W1, P0, hist0, hist1, WtG, bar);
        coop_sort_kernel<<<SORT_BLOCKS, 256, 0, stream>>>(P0, P1, hist0, hist1, hist2,
                                                          RS, out_ids, bar);
        fused_kernel<<<NELEM / FBM, 256, 0, stream>>>(P1, RS, WtG, emb, b1, enc, out_enc);
    } else {
        unsigned int*   G   = (unsigned int*)(ws);
        unsigned short* RS  = (unsigned short*)(ws + 65536);
        unsigned short* WtG = (unsigned short*)(ws + 98432);

        hipFuncSetAttribute((const void*)sort_transpose_kernel,
                            hipFuncAttributeMaxDynamicSharedMemorySize, SORT_SMEM);
        sort_transpose_kernel<<<1 + 96, 1024, SORT_SMEM, stream>>>(
            vocab_ids, W1, G, RS, WtG, out_ids);
        fused_kernel<<<NELEM / FBM, 256, 0, stream>>>(G, RS, WtG, emb, b1, enc, out_enc);
    }
}

// Round 9
// 66.907 us; speedup vs baseline: 1.0730x; 1.0730x over previous
//
#include <hip/hip_runtime.h>
#include <hip/hip_bf16.h>

#define NELEM 16384
#define DIN 768
#define DMID 128
#define DOUT 4

typedef __attribute__((ext_vector_type(8))) short short8;
typedef __attribute__((ext_vector_type(4))) float f32x4;

__device__ __forceinline__ unsigned f2bf(float f) {
    unsigned u = __float_as_uint(f);
    return (u + 0x7FFFu + ((u >> 16) & 1u)) >> 16;   // RNE bf16
}

// word = vocab<<14 | e (e = b*512+s); key = word>>9; idx = word&16383;
// vocab = word>>14; batch = (word>>9)&31.

// ===========================================================================
// FAST PATH ws layout:
//   P0@0(64K) P1@65536(64K) hist0@131072(64K) hist1@196608(64K) hist2@262144(64K)
//   RS@327680(32772B) WtG@360512(192K) bar@557120(u32) gsum@557184(64 u32)
// hist layout: hist[block*256 + digit]  (lane-coalesced row scans).
// All cross-block-shared data (P0,P1,hist*,gsum) accessed ONLY via relaxed
// agent-scope atomics -> coherent point, L2 stays clean -> cheap barriers.
// ===========================================================================
#define FAST_WS 557440
#define SB 64   // sort blocks

__device__ __forceinline__ unsigned aload(const unsigned* p) {
    return __hip_atomic_load((unsigned*)p, __ATOMIC_RELAXED, __HIP_MEMORY_SCOPE_AGENT);
}
__device__ __forceinline__ void astore(unsigned* p, unsigned v) {
    __hip_atomic_store(p, v, __ATOMIC_RELAXED, __HIP_MEMORY_SCOPE_AGENT);
}
__device__ __forceinline__ void aadd(unsigned* p, unsigned v) {
    __hip_atomic_fetch_add(p, v, __ATOMIC_RELAXED, __HIP_MEMORY_SCOPE_AGENT);
}

// threshold barrier: counter zeroed by hipMemsetAsync each launch.
__device__ __forceinline__ void gbar(unsigned* cnt, unsigned thresh) {
    __syncthreads();
    if (threadIdx.x == 0) {
        __hip_atomic_fetch_add(cnt, 1u, __ATOMIC_ACQ_REL, __HIP_MEMORY_SCOPE_AGENT);
        while (__hip_atomic_load(cnt, __ATOMIC_RELAXED, __HIP_MEMORY_SCOPE_AGENT) < thresh)
            __builtin_amdgcn_s_sleep(1);
        (void)__hip_atomic_load(cnt, __ATOMIC_ACQUIRE, __HIP_MEMORY_SCOPE_AGENT);
    }
    __syncthreads();
}

// one stable 8-bit scatter pass; 256 elems/block, 64 blocks.
template <bool HASNEXT>
__device__ __forceinline__ void scatter_pass(
    const unsigned* __restrict__ src, unsigned* __restrict__ dst,
    const unsigned* __restrict__ histCur, unsigned* __restrict__ histNext,
    int shift, int nshift, int blk, int t,
    unsigned* base_lds, unsigned* whist, unsigned* wsum) {
    const int lane = t & 63;
    const int w = t >> 6;

    unsigned x = aload(&src[blk * 256 + t]);
    unsigned d = (x >> shift) & 255u;

    whist[t] = 0; whist[256 + t] = 0; whist[512 + t] = 0; whist[768 + t] = 0;

    // digit-row scan (digit = t): rowsum over all blocks + prefix over blocks < blk
    unsigned rowsum = 0, myprefix = 0;
#pragma unroll
    for (int b = 0; b < SB; ++b) {
        unsigned h = aload(&histCur[b * 256 + t]);   // lanes read consecutive dwords
        rowsum += h;
        if (b < blk) myprefix += h;
    }
    // block-exclusive scan of 256 digit rowsums
    unsigned inc = rowsum;
#pragma unroll
    for (int off = 1; off < 64; off <<= 1) {
        unsigned y = __shfl_up(inc, off);
        if (lane >= off) inc += y;
    }
    if (lane == 63) wsum[w] = inc;
    __syncthreads();
    unsigned wo = 0;
    for (int w2 = 0; w2 < w; ++w2) wo += wsum[w2];
    base_lds[t] = wo + (inc - rowsum) + myprefix;

    // stable in-wave rank via 8-ballot match-any
    unsigned long long m = ~0ull;
#pragma unroll
    for (int bit = 0; bit < 8; ++bit) {
        unsigned long long bb = __ballot((d >> bit) & 1u);
        m &= ((d >> bit) & 1u) ? bb : ~bb;
    }
    int inrank = __popcll(m & ((1ull << lane) - 1ull));
    if (inrank == 0) whist[w * 256 + d] = (unsigned)__popcll(m);
    __syncthreads();
    unsigned cross = 0;
    for (int w2 = 0; w2 < w; ++w2) cross += whist[w2 * 256 + d];
    unsigned dstpos = base_lds[d] + cross + (unsigned)inrank;
    astore(&dst[dstpos], x);
    if (HASNEXT) {
        unsigned dn = (x >> nshift) & 255u;
        aadd(&histNext[(dstpos >> 8) * 256 + dn], 1u);
    }
    __syncthreads();   // whist/base_lds safe for next phase
}

// K1: mega sort kernel. 64 blocks x 256 thr. build+transpose, 3 scatters,
// unique, RS/ids — 5 internal barriers, zero kernel boundaries.
__global__ __launch_bounds__(256) void sort_mega_kernel(
    const int* __restrict__ vocab_ids, const float* __restrict__ W1,
    unsigned* __restrict__ P0, unsigned* __restrict__ P1,
    unsigned* __restrict__ hist0, unsigned* __restrict__ hist1,
    unsigned* __restrict__ hist2,
    unsigned short* __restrict__ RS, unsigned short* __restrict__ WtG,
    float* __restrict__ out_ids,
    unsigned* __restrict__ bar, unsigned* __restrict__ gsum) {
    __shared__ unsigned base_lds[256];
    __shared__ unsigned whist[4 * 256];
    __shared__ unsigned wsum[4];
    const int t = threadIdx.x;
    const int blk = blockIdx.x;

    // ---- phase 0: build words + pass-0 hist + zero hist1/2 + W1 transpose ----
    const int e = blk * 256 + t;
    {
        whist[t] = 0;
        unsigned word = ((unsigned)vocab_ids[e] << 14) | (unsigned)e;
        astore(&P0[e], word);
        __syncthreads();
        atomicAdd(&whist[(word >> 9) & 255u], 1u);   // LDS
        __syncthreads();
        astore(&hist0[blk * 256 + t], whist[t]);
        astore(&hist1[blk * 256 + t], 0u);
        astore(&hist2[blk * 256 + t], 0u);
        // transpose W1 (768x128 f32) -> WtG (128x768 bf16); coalesced reads
#pragma unroll
        for (int i = 0; i < 6; ++i) {
            int j = blk * 1536 + i * 256 + t;        // 0..98303
            int k = j >> 7;                          // row of W1
            int c = j & 127;                         // col of W1
            WtG[c * DIN + k] = (unsigned short)f2bf(W1[j]);
        }
        __syncthreads();
    }
    gbar(bar, SB * 1);

    scatter_pass<true >(P0, P1, hist0, hist1, 9, 17, blk, t, base_lds, whist, wsum);
    gbar(bar, SB * 2);
    scatter_pass<true >(P1, P0, hist1, hist2, 17, 25, blk, t, base_lds, whist, wsum);
    gbar(bar, SB * 3);
    scatter_pass<false>(P0, P1, hist2, nullptr, 25, 0, blk, t, base_lds, whist, wsum);
    gbar(bar, SB * 4);

    // ---- unique phase A: flags + per-block count ----
    unsigned word = aload(&P1[e]);
    unsigned key = word >> 9;
    bool f = (e == 0) || ((aload(&P1[e - 1]) >> 9) != key);
    {
        const int lane = t & 63;
        const int w = t >> 6;
        unsigned long long bb = __ballot(f ? 1 : 0);
        unsigned lrank = (unsigned)__popcll(bb & ((1ull << lane) - 1ull));
        if (lane == 0) wsum[w] = (unsigned)__popcll(bb);
        __syncthreads();
        unsigned woff = 0, btot = 0;
#pragma unroll
        for (int w2 = 0; w2 < 4; ++w2) {
            if (w2 < w) woff += wsum[w2];
            btot += wsum[w2];
        }
        if (t == 0) astore(&gsum[blk], btot);
        gbar(bar, SB * 5);
        // ---- phase B: cross-block prefix (staged via LDS) + writes ----
        if (t < SB) base_lds[t] = aload(&gsum[t]);
        __syncthreads();
        unsigned prefix = 0, U = 0;
#pragma unroll
        for (int b = 0; b < SB; ++b) {
            unsigned g = base_lds[b];
            if (b < blk) prefix += g;
            U += g;
        }
        if (f) {
            unsigned r = prefix + woff + lrank;
            RS[r] = (unsigned short)e;
            out_ids[2 * r + 0] = (float)(word >> 14);
            out_ids[2 * r + 1] = (float)(key & 31u);
        }
        if ((unsigned)e >= U) {
            RS[e] = (unsigned short)NELEM;
            out_ids[2 * e + 0] = 0.0f;
            out_ids[2 * e + 1] = 0.0f;
        }
        if (e == 0) RS[NELEM] = (unsigned short)NELEM;
    }
}

// ===========================================================================
// FALLBACK (proven R6 path) if ws is too small.
// ===========================================================================
#define SORT_SMEM (65536 + 65536 + 4096 + 64)

__global__ __launch_bounds__(1024) void sort_transpose_kernel(
    const int* __restrict__ vocab_ids,
    const float* __restrict__ W1,
    unsigned int* __restrict__ G,
    unsigned short* __restrict__ RS,
    unsigned short* __restrict__ WtG,
    float* __restrict__ out_ids) {
    const int t = threadIdx.x;
    if (blockIdx.x != 0) {
        int idx = (blockIdx.x - 1) * 1024 + t;
        if (idx < DMID * DIN) {
            int c = idx / DIN;
            int k = idx - c * DIN;
            WtG[idx] = (unsigned short)f2bf(W1[k * DMID + c]);
        }
        return;
    }
    extern __shared__ char smem[];
    unsigned* Gs     = (unsigned*)smem;
    unsigned* histDM = (unsigned*)(smem + 65536);
    unsigned* sums   = (unsigned*)(smem + 131072);
    unsigned* totalU = (unsigned*)(smem + 135168);

    for (int e = t; e < NELEM; e += 1024)
        Gs[e] = ((unsigned)vocab_ids[e] << 14) | (unsigned)e;
    __syncthreads();

    for (int pass = 0; pass < 6; ++pass) {
        const int shift = 9 + pass * 4;
        unsigned v[16];
#pragma unroll
        for (int i = 0; i < 16; ++i) v[i] = Gs[t * 16 + i];
#pragma unroll
        for (int d = 0; d < 16; ++d) histDM[d * 1024 + t] = 0;
#pragma unroll
        for (int i = 0; i < 16; ++i) histDM[((v[i] >> shift) & 15u) * 1024 + t] += 1;
        __syncthreads();
        unsigned lex[16]; unsigned run = 0;
#pragma unroll
        for (int i = 0; i < 16; ++i) { unsigned x = histDM[t * 16 + i]; lex[i] = run; run += x; }
        sums[t] = run;
        __syncthreads();
        if (t < 64) {
            unsigned s[16]; unsigned tot = 0;
#pragma unroll
            for (int i = 0; i < 16; ++i) { unsigned x = sums[t * 16 + i]; s[i] = tot; tot += x; }
            unsigned incv = tot;
#pragma unroll
            for (int off = 1; off < 64; off <<= 1) {
                unsigned y = __shfl_up(incv, off);
                if (t >= off) incv += y;
            }
            unsigned excl = incv - tot;
#pragma unroll
            for (int i = 0; i < 16; ++i) sums[t * 16 + i] = excl + s[i];
        }
        __syncthreads();
#pragma unroll
        for (int i = 0; i < 16; ++i) histDM[t * 16 + i] = sums[t] + lex[i];
        __syncthreads();
        unsigned mycnt[16];
#pragma unroll
        for (int d = 0; d < 16; ++d) mycnt[d] = histDM[d * 1024 + t];
#pragma unroll
        for (int i = 0; i < 16; ++i) {
            unsigned d = (v[i] >> shift) & 15u;
            Gs[mycnt[d]++] = v[i];
        }
        __syncthreads();
    }

    unsigned v[16];
#pragma unroll
    for (int i = 0; i < 16; ++i) v[i] = Gs[t * 16 + i];
    unsigned pk = (t == 0) ? 0xFFFFFFFFu : (Gs[t * 16 - 1] >> 9);
    unsigned fm = 0;
#pragma unroll
    for (int i = 0; i < 16; ++i) {
        unsigned key = v[i] >> 9;
        if (key != pk) fm |= (1u << i);
        pk = key;
    }
    sums[t] = (unsigned)__popc(fm);
    __syncthreads();
    if (t < 64) {
        unsigned s[16]; unsigned tot = 0;
#pragma unroll
        for (int i = 0; i < 16; ++i) { unsigned x = sums[t * 16 + i]; s[i] = tot; tot += x; }
        unsigned incv = tot;
#pragma unroll
        for (int off = 1; off < 64; off <<= 1) {
            unsigned y = __shfl_up(incv, off);
            if (t >= off) incv += y;
        }
        unsigned excl = incv - tot;
#pragma unroll
        for (int i = 0; i < 16; ++i) sums[t * 16 + i] = excl + s[i];
        if (t == 63) *totalU = incv;
    }
    __syncthreads();
    unsigned r = sums[t];
#pragma unroll
    for (int i = 0; i < 16; ++i) {
        if (fm & (1u << i)) {
            RS[r] = (unsigned short)(t * 16 + i);
            out_ids[2 * r + 0] = (float)(v[i] >> 14);
            out_ids[2 * r + 1] = (float)((v[i] >> 9) & 31u);
            ++r;
        }
    }
    const unsigned U = *totalU;
    for (int u = t; u < NELEM; u += 1024) {
        if ((unsigned)u >= U) {
            RS[u] = (unsigned short)NELEM;
            out_ids[2 * u + 0] = 0.0f;
            out_ids[2 * u + 1] = 0.0f;
        }
        G[u] = Gs[u];
    }
    if (t == 0) RS[NELEM] = (unsigned short)NELEM;
}

// ===========================================================================
// K2: MFMA fused kernel (proven). 1024 blocks x 256 thr, 16 rows/block.
// ===========================================================================
#define FBM 16
__global__ __launch_bounds__(256) void fused_kernel(
    const unsigned* __restrict__ G,
    const unsigned short* __restrict__ RS,
    const unsigned short* __restrict__ WtG,
    const float* __restrict__ emb,
    const float* __restrict__ b1,
    const float* __restrict__ enc,
    float* __restrict__ out_enc) {
    __shared__ char smem[20736];

    const int t = threadIdx.x;
    const int u0 = blockIdx.x * FBM;
    const int l = t & 63;
    const int w = t >> 6;

    const int ar = t >> 4;
    const int ak4 = t & 15;
    const int rs_a = (int)RS[u0 + ar];
    const int re_a = (int)RS[u0 + ar + 1];

    f32x4 acc0 = {0.f, 0.f, 0.f, 0.f};
    f32x4 acc1 = {0.f, 0.f, 0.f, 0.f};

    for (int kk = 0; kk < DIN; kk += 64) {
        __syncthreads();
        {
            float s0 = 0.f, s1 = 0.f, s2 = 0.f, s3 = 0.f;
            const float* base = emb + (size_t)(kk + ak4 * 4);
            for (int p = rs_a; p < re_a; ++p) {
                unsigned idx = G[p] & 16383u;
                const float4 e4 = *(const float4*)(base + (size_t)idx * DIN);
                s0 += e4.x; s1 += e4.y; s2 += e4.z; s3 += e4.w;
            }
            uint2 packed;
            packed.x = f2bf(s0) | (f2bf(s1) << 16);
            packed.y = f2bf(s2) | (f2bf(s3) << 16);
            *(uint2*)(smem + ar * 144 + ak4 * 8) = packed;
        }
        {
#pragma unroll
            for (int i = 0; i < 4; ++i) {
                int q = t + i * 256;
                int c = q >> 3;
                int uo = q & 7;
                uint4 dv = *(const uint4*)(WtG + (size_t)c * DIN + kk + uo * 8);
                *(uint4*)(smem + 2304 + c * 144 + uo * 16) = dv;
            }
        }
        __syncthreads();
        {
            const int arow = l & 15;
            const int ull = l >> 4;
#pragma unroll
            for (int kf = 0; kf < 2; ++kf) {
                short8 aF = *(const short8*)(smem + arow * 144 + kf * 64 + ull * 16);
                short8 bF0 = *(const short8*)(smem + 2304 + (w * 32 + arow) * 144 + kf * 64 + ull * 16);
                short8 bF1 = *(const short8*)(smem + 2304 + (w * 32 + 16 + arow) * 144 + kf * 64 + ull * 16);
                acc0 = __builtin_amdgcn_mfma_f32_16x16x32_bf16(aF, bF0, acc0, 0, 0, 0);
                acc1 = __builtin_amdgcn_mfma_f32_16x16x32_bf16(aF, bF1, acc1, 0, 0, 0);
            }
        }
    }
    __syncthreads();
    {
        float* Hs = (float*)smem;
        const int col0 = w * 32 + (l & 15);
        const int rbase = (l >> 4) * 4;
#pragma unroll
        for (int reg = 0; reg < 4; ++reg) {
            Hs[(rbase + reg) * 132 + col0] = tanhf(acc0[reg] + b1[col0]);
            Hs[(rbase + reg) * 132 + col0 + 16] = tanhf(acc1[reg] + b1[col0 + 16]);
        }
    }
    __syncthreads();
    {
        const float* Hs = (const float*)smem;
        const int r = t >> 4;
        const int g = t & 15;
        const int u = u0 + r;
        const int rs = (int)RS[u];
        const int re = (int)RS[u + 1];
        unsigned vocab = (rs < re) ? (G[rs] >> 14) : 0u;
        const float4* wrow = (const float4*)(enc + (size_t)vocab * (DMID * DOUT));
        float ax = 0.f, ay = 0.f, az = 0.f, aw = 0.f;
#pragma unroll
        for (int jj = 0; jj < 8; ++jj) {
            int j = jj * 16 + g;
            float4 w4 = wrow[j];
            float hv = Hs[r * 132 + j];
            ax += hv * w4.x; ay += hv * w4.y; az += hv * w4.z; aw += hv * w4.w;
        }
#pragma unroll
        for (int off = 1; off < 16; off <<= 1) {
            ax += __shfl_xor(ax, off);
            ay += __shfl_xor(ay, off);
            az += __shfl_xor(az, off);
            aw += __shfl_xor(aw, off);
        }
        if (g == 0) {
            float4 o;
            o.x = 1.f / (1.f + expf(-ax));
            o.y = 1.f / (1.f + expf(-ay));
            o.z = 1.f / (1.f + expf(-az));
            o.w = 1.f / (1.f + expf(-aw));
            *(float4*)(out_enc + (size_t)u * 4) = o;
        }
    }
}

// ---------------------------------------------------------------------------
extern "C" void kernel_launch(void* const* d_in, const int* in_sizes, int n_in,
                              void* d_out, int out_size, void* d_ws, size_t ws_size,
                              hipStream_t stream) {
    const int*   vocab_ids = (const int*)d_in[0];
    const float* emb       = (const float*)d_in[1];
    const float* W1        = (const float*)d_in[2];
    const float* b1        = (const float*)d_in[3];
    const float* enc       = (const float*)d_in[4];
    float* out = (float*)d_out;

    float* out_ids = out;               // 32768 f32
    float* out_enc = out + NELEM * 2;   // 65536 f32

    char* ws = (char*)d_ws;

    if (ws_size >= FAST_WS) {
        unsigned*       P0    = (unsigned*)(ws + 0);
        unsigned*       P1    = (unsigned*)(ws + 65536);
        unsigned*       hist0 = (unsigned*)(ws + 131072);
        unsigned*       hist1 = (unsigned*)(ws + 196608);
        unsigned*       hist2 = (unsigned*)(ws + 262144);
        unsigned short* RS    = (unsigned short*)(ws + 327680);
        unsigned short* WtG   = (unsigned short*)(ws + 360512);
        unsigned*       bar   = (unsigned*)(ws + 557120);
        unsigned*       gsum  = (unsigned*)(ws + 557184);

        hipMemsetAsync(bar, 0, 4, stream);   // barrier counter = 0 each launch
        sort_mega_kernel<<<SB, 256, 0, stream>>>(vocab_ids, W1, P0, P1,
                                                 hist0, hist1, hist2,
                                                 RS, WtG, out_ids, bar, gsum);
        fused_kernel<<<NELEM / FBM, 256, 0, stream>>>(P1, RS, WtG, emb, b1, enc, out_enc);
    } else {
        unsigned int*   G   = (unsigned int*)(ws);
        unsigned short* RS  = (unsigned short*)(ws + 65536);
        unsigned short* WtG = (unsigned short*)(ws + 98432);

        hipFuncSetAttribute((const void*)sort_transpose_kernel,
                            hipFuncAttributeMaxDynamicSharedMemorySize, SORT_SMEM);
        sort_transpose_kernel<<<1 + 96, 1024, SORT_SMEM, stream>>>(
            vocab_ids, W1, G, RS, WtG, out_ids);
        fused_kernel<<<NELEM / FBM, 256, 0, stream>>>(G, RS, WtG, emb, b1, enc, out_enc);
    }
}